// Round 15
// baseline (344.941 us; speedup 1.0000x reference)
//
#include <hip/hip_runtime.h>
#include <hip/hip_bf16.h>

// FP32 tensors on device (R2). H tables bf16 (R4). MLP via bf16 MFMA (R5).
// Edge phase: R11 rank-array pass1 + simple scatter (R13-verified). Packed 4B
// CSR (R9/R10). Agg: 4-wave (row,half) blocks, XCD half-split, uint2 gathers
// (R12-R14). R15: agg3 fixed-overhead strip — denominator fused into the
// parity reduction (kills the 8-barrier 256-tree) and double-buffered edge
// staging (1 barrier/chunk instead of 2; CSR loads overlap gathers).
#define HIDC 128
typedef __hip_bfloat16 bf16;
typedef __attribute__((ext_vector_type(8))) short short8;   // 8 bf16 (4 VGPR)
typedef __attribute__((ext_vector_type(4))) float floatx4;  // 4 fp32 acc

#define CHUNK 4096   // edges per pass1 block

__device__ __forceinline__ short f2b(float f) {
    unsigned int u = __builtin_bit_cast(unsigned int, f);
    u += 0x7fff + ((u >> 16) & 1);          // RNE
    return (short)(u >> 16);
}

__device__ __forceinline__ uint packe(int s, float ev) {
    float w = __expf(ev);                    // exp > 0, |logit| <= ~9 -> bf16-safe
    return ((uint)s << 16) | (uint)(unsigned short)f2b(w);
}

// ---- prep: zero workspace | wa = W@a (+c_edge) | W1/W2 -> bf16 transposed ----
__global__ void __launch_bounds__(256) r15_prep(
    int* __restrict__ zptr, int zwords, int nzb,
    const float* __restrict__ W_dd, const float* __restrict__ W_dp, const float* __restrict__ W_cp,
    const float* __restrict__ a0, const float* __restrict__ a1, const float* __restrict__ a2,
    const float* __restrict__ a3, const float* __restrict__ a4, const float* __restrict__ a5,
    const float* __restrict__ W_edge, const float* __restrict__ a_edge,
    float* __restrict__ wa, float* __restrict__ c_edge,
    const float* __restrict__ W1, short* __restrict__ Wt1, int nT1,
    const float* __restrict__ W2, short* __restrict__ Wt2)
{
    int b = blockIdx.x;
    int tid = threadIdx.x;
    if (b < nzb) {
        int i = b * 256 + tid;
        if (i < zwords) zptr[i] = 0;
        return;
    }
    b -= nzb;
    if (b < 7) {
        __shared__ float as[HIDC];
        int k = tid;
        if (b < 6) {
            const float* W = (b < 2) ? W_dd : (b < 4) ? W_dp : W_cp;
            const float* a = (b == 0) ? a0 : (b == 1) ? a1 : (b == 2) ? a2 : (b == 3) ? a3 : (b == 4) ? a4 : a5;
            if (k < HIDC) as[k] = a[k];
            __syncthreads();
            if (k < HIDC) {
                float s = 0.f;
#pragma unroll 8
                for (int c = 0; c < HIDC; c++) s = fmaf(W[k * HIDC + c], as[c], s);
                wa[b * HIDC + k] = s;
            }
        } else {
            if (k < HIDC) as[k] = W_edge[k] * a_edge[k];
            __syncthreads();
#pragma unroll
            for (int off = 64; off > 0; off >>= 1) { if (k < off) as[k] += as[k + off]; __syncthreads(); }
            if (k == 0) c_edge[0] = as[0];
        }
        return;
    }
    b -= 7;
    const float* W; short* Wt; int K, N, k0, n0;
    if (b < nT1) { W = W1; Wt = Wt1; K = 384; N = 768; k0 = (b / 24) * 32; n0 = (b % 24) * 32; }
    else { b -= nT1; W = W2; Wt = Wt2; K = 768; N = 256; k0 = (b / 8) * 32; n0 = (b % 8) * 32; }
    __shared__ short T[32 * 34];
    int cc = tid & 31, rr = tid >> 5;
#pragma unroll
    for (int it = 0; it < 4; it++) {
        int r = it * 8 + rr;
        T[r * 34 + cc] = f2b(W[(size_t)(k0 + r) * N + n0 + cc]);
    }
    __syncthreads();
#pragma unroll
    for (int it = 0; it < 4; it++) {
        int r = it * 8 + rr;
        Wt[(size_t)(n0 + r) * K + k0 + cc] = T[cc * 34 + r];
    }
}

// ---- attention scalars ----
__global__ void __launch_bounds__(256) r15_scalars(
    const float* __restrict__ drug_emb, const float* __restrict__ prot_emb, const float* __restrict__ cell_emb,
    const int* __restrict__ x_drug, const int* __restrict__ x_prot, const int* __restrict__ x_cell,
    const float* __restrict__ wa,
    float* __restrict__ ssrc_dd, float* __restrict__ sdst_dd, float* __restrict__ sdst_dp,
    float* __restrict__ ssrc_dp, float* __restrict__ ssrc_cp, float* __restrict__ sdst_cp,
    int nd, int npr, int ncl)
{
    int g = blockIdx.x * 4 + (threadIdx.x >> 6);
    int l = threadIdx.x & 63;
    const float2* wa2 = (const float2*)wa;
    if (g < nd) {
        int id = x_drug[g];
        float2 e = ((const float2*)drug_emb)[(size_t)id * 64 + l];
        float2 w0 = wa2[0 * 64 + l], w1 = wa2[1 * 64 + l], w3 = wa2[3 * 64 + l];
        float p0 = e.x * w0.x + e.y * w0.y;
        float p1 = e.x * w1.x + e.y * w1.y;
        float p2 = e.x * w3.x + e.y * w3.y;
#pragma unroll
        for (int off = 32; off > 0; off >>= 1) {
            p0 += __shfl_xor(p0, off, 64);
            p1 += __shfl_xor(p1, off, 64);
            p2 += __shfl_xor(p2, off, 64);
        }
        if (l == 0) { ssrc_dd[g] = p0; sdst_dd[g] = p1; sdst_dp[g] = p2; }
    } else if (g < nd + npr) {
        int r = g - nd;
        int id = x_prot[r];
        float2 e = ((const float2*)prot_emb)[(size_t)id * 64 + l];
        float2 w2 = wa2[2 * 64 + l], w4 = wa2[4 * 64 + l];
        float p0 = e.x * w2.x + e.y * w2.y;
        float p1 = e.x * w4.x + e.y * w4.y;
#pragma unroll
        for (int off = 32; off > 0; off >>= 1) {
            p0 += __shfl_xor(p0, off, 64);
            p1 += __shfl_xor(p1, off, 64);
        }
        if (l == 0) { ssrc_dp[r] = p0; ssrc_cp[r] = p1; }
    } else if (g < nd + npr + ncl) {
        int r = g - nd - npr;
        int id = x_cell[r];
        float2 e = ((const float2*)cell_emb)[(size_t)id * 64 + l];
        float2 w5 = wa2[5 * 64 + l];
        float p0 = e.x * w5.x + e.y * w5.y;
#pragma unroll
        for (int off = 32; off > 0; off >>= 1) p0 += __shfl_xor(p0, off, 64);
        if (l == 0) sdst_cp[r] = p0;
    }
}

// ---- fused node GEMMs: drug blocks -> H_dd; protein blocks -> H_dp AND H_cp ----
__global__ void __launch_bounds__(128) r15_node_gemm(
    const float* __restrict__ drug_emb, const int* __restrict__ x_drug,
    const float* __restrict__ W_dd, bf16* __restrict__ H_dd, int ndb,
    const float* __restrict__ prot_emb, const int* __restrict__ x_prot,
    const float* __restrict__ W_dp, const float* __restrict__ W_cp,
    bf16* __restrict__ H_dp, bf16* __restrict__ H_cp)
{
    __shared__ int ids[16];
    __shared__ float xs[16 * HIDC];
    int bb = blockIdx.x;
    bool isdrug = bb < ndb;
    int r0 = (isdrug ? bb : bb - ndb) * 16;
    const float* emb = isdrug ? drug_emb : prot_emb;
    const int* idx = isdrug ? x_drug : x_prot;
    int tid = threadIdx.x;
    if (tid < 16) ids[tid] = idx[r0 + tid];
    __syncthreads();
    for (int t = tid; t < 16 * HIDC; t += 128) {
        int r = t >> 7, k = t & 127;
        xs[t] = emb[(size_t)ids[r] * HIDC + k];
    }
    __syncthreads();
    int c = tid;
    if (isdrug) {
        float acc[16];
#pragma unroll
        for (int r = 0; r < 16; r++) acc[r] = 0.f;
        for (int k = 0; k < HIDC; k += 4) {
            float w0 = W_dd[(k + 0) * HIDC + c];
            float w1 = W_dd[(k + 1) * HIDC + c];
            float w2 = W_dd[(k + 2) * HIDC + c];
            float w3 = W_dd[(k + 3) * HIDC + c];
#pragma unroll
            for (int r = 0; r < 16; r++) {
                float4 x = *(const float4*)&xs[r * HIDC + k];
                acc[r] = fmaf(x.x, w0, fmaf(x.y, w1, fmaf(x.z, w2, fmaf(x.w, w3, acc[r]))));
            }
        }
#pragma unroll
        for (int r = 0; r < 16; r++) H_dd[(size_t)(r0 + r) * HIDC + c] = __float2bfloat16(acc[r]);
    } else {
        float accA[16], accB[16];
#pragma unroll
        for (int r = 0; r < 16; r++) { accA[r] = 0.f; accB[r] = 0.f; }
        for (int k = 0; k < HIDC; k += 2) {
            float a0 = W_dp[(k + 0) * HIDC + c];
            float a1 = W_dp[(k + 1) * HIDC + c];
            float b0 = W_cp[(k + 0) * HIDC + c];
            float b1 = W_cp[(k + 1) * HIDC + c];
#pragma unroll
            for (int r = 0; r < 16; r++) {
                float2 x = *(const float2*)&xs[r * HIDC + k];
                accA[r] = fmaf(x.x, a0, fmaf(x.y, a1, accA[r]));
                accB[r] = fmaf(x.x, b0, fmaf(x.y, b1, accB[r]));
            }
        }
#pragma unroll
        for (int r = 0; r < 16; r++) {
            H_dp[(size_t)(r0 + r) * HIDC + c] = __float2bfloat16(accA[r]);
            H_cp[(size_t)(r0 + r) * HIDC + c] = __float2bfloat16(accB[r]);
        }
    }
}

// ---- pass1, LDS-privatized: local ranks + per-bin global base atomics ----
__global__ void __launch_bounds__(256) r15_edge_pass1(
    const int* __restrict__ dst_dd, const float* __restrict__ attr_dd, int E_dd, int nb_dd,
    const int* __restrict__ dst_dp, int E_dp, int nb_dp,
    const int* __restrict__ dst_cp, int E_cp,
    int nd, int ncl,
    int* __restrict__ cnt_dd, float* __restrict__ attr_sum,
    int* __restrict__ cnt_dp, int* __restrict__ cnt_cp,
    int* __restrict__ rank_dd, int* __restrict__ rank_dp, int* __restrict__ rank_cp)
{
    __shared__ int lcnt[4096];
    __shared__ float lattr[4096];
    int bid = blockIdx.x;
    const int* dst; const float* attr = nullptr; int E, e0, bins;
    int* gcnt; int* rank;
    if (bid < nb_dd) {
        dst = dst_dd; attr = attr_dd; E = E_dd; e0 = bid * CHUNK; bins = nd;
        gcnt = cnt_dd; rank = rank_dd;
    } else if (bid < nb_dd + nb_dp) {
        dst = dst_dp; E = E_dp; e0 = (bid - nb_dd) * CHUNK; bins = nd;
        gcnt = cnt_dp; rank = rank_dp;
    } else {
        dst = dst_cp; E = E_cp; e0 = (bid - nb_dd - nb_dp) * CHUNK; bins = ncl;
        gcnt = cnt_cp; rank = rank_cp;
    }
    int tid = threadIdx.x;
    for (int b = tid; b < bins; b += 256) { lcnt[b] = 0; if (attr) lattr[b] = 0.f; }
    __syncthreads();
    int e1 = min(e0 + CHUNK, E);
    for (int i = e0 + tid; i < e1; i += 256) {
        int d = dst[i];
        rank[i] = atomicAdd(&lcnt[d], 1);
        if (attr) atomicAdd(&lattr[d], attr[i]);
    }
    __syncthreads();
    for (int b = tid; b < bins; b += 256) {
        int c = lcnt[b];
        if (c > 0) {
            lcnt[b] = atomicAdd(&gcnt[b], c);
            if (attr) atomicAdd(&attr_sum[b], lattr[b]);
        }
    }
    __syncthreads();
    for (int i = e0 + tid; i < e1; i += 256) {
        rank[i] += lcnt[dst[i]];
    }
}

// ---- three exclusive scans; scan 0 adds +1/elem (dd self-loops) ----
__global__ void __launch_bounds__(1024) r15_exscan3(
    const int* __restrict__ in0, int* __restrict__ out0, int n0,
    const int* __restrict__ in1, int* __restrict__ out1, int n1,
    const int* __restrict__ in2, int* __restrict__ out2, int n2)
{
    const int* in; int* out; int n; int inc;
    if (blockIdx.x == 0)      { in = in0; out = out0; n = n0; inc = 1; }
    else if (blockIdx.x == 1) { in = in1; out = out1; n = n1; inc = 0; }
    else                      { in = in2; out = out2; n = n2; inc = 0; }
    __shared__ int buf[1024];
    __shared__ int carry;
    int tid = threadIdx.x;
    if (tid == 0) carry = 0;
    __syncthreads();
    for (int base = 0; base < n; base += 1024) {
        int i = base + tid;
        int v = (i < n) ? (in[i] + inc) : 0;
        buf[tid] = v; __syncthreads();
        for (int off = 1; off < 1024; off <<= 1) {
            int t = (tid >= off) ? buf[tid - off] : 0;
            __syncthreads();
            buf[tid] += t;
            __syncthreads();
        }
        int c0 = carry;
        int incl = buf[tid];
        if (i < n) out[i] = c0 + incl - v;
        __syncthreads();
        if (tid == 1023) carry = c0 + buf[1023];
        __syncthreads();
    }
    if (tid == 0) out[n] = carry;
}

// ---- scatter into packed CSR, no atomics (slot = rs[d]+rank) ----
__global__ void r15_scatter(
    const int* __restrict__ ei_dd, const float* __restrict__ attr_dd, int E_dd, int nd,
    const int* __restrict__ src_dp, const int* __restrict__ dst_dp, int E_dp,
    const int* __restrict__ src_cp, const int* __restrict__ dst_cp, int E_cp,
    const int* __restrict__ rank_dd, const int* __restrict__ rank_dp, const int* __restrict__ rank_cp,
    const int* __restrict__ deg_dd, const float* __restrict__ attr_sum,
    const float* __restrict__ c_edge_ptr,
    const float* __restrict__ ssrc_dd, const float* __restrict__ sdst_dd,
    const float* __restrict__ ssrc_dp, const float* __restrict__ sdst_dp,
    const float* __restrict__ ssrc_cp, const float* __restrict__ sdst_cp,
    const int* __restrict__ rs_dd, const int* __restrict__ rs_dp, const int* __restrict__ rs_cp,
    uint* __restrict__ csr_dd, uint* __restrict__ csr_dp, uint* __restrict__ csr_cp)
{
    int i = blockIdx.x * 256 + threadIdx.x;
    if (i < E_dd) {
        int s = ei_dd[i], d = ei_dd[E_dd + i];
        float ev = ssrc_dd[s] + sdst_dd[d] + attr_dd[i] * c_edge_ptr[0];
        ev = (ev > 0.f) ? ev : 0.2f * ev;
        csr_dd[rs_dd[d] + rank_dd[i]] = packe(s, ev);
        return;
    }
    i -= E_dd;
    if (i < nd) {   // dd self-loops with mean-attr fill
        int d = i;
        int dg = deg_dd[d];
        float mean = attr_sum[d] / fmaxf((float)dg, 1.0f);
        float ev = ssrc_dd[d] + sdst_dd[d] + mean * c_edge_ptr[0];
        ev = (ev > 0.f) ? ev : 0.2f * ev;
        csr_dd[rs_dd[d] + dg] = packe(d, ev);
        return;
    }
    i -= nd;
    if (i < E_dp) {
        int d = dst_dp[i], s = src_dp[i];
        float ev = ssrc_dp[s] + sdst_dp[d];
        ev = (ev > 0.f) ? ev : 0.2f * ev;
        csr_dp[rs_dp[d] + rank_dp[i]] = packe(s, ev);
        return;
    }
    i -= E_dp;
    if (i < E_cp) {
        int d = dst_cp[i], s = src_cp[i];
        float ev = ssrc_cp[s] + sdst_cp[d];
        ev = (ev > 0.f) ? ev : 0.2f * ev;
        csr_cp[rs_cp[d] + rank_cp[i]] = packe(s, ev);
    }
}

// ---- softmax+aggregate: 256-thr block = 4 waves on ONE (row, half).
// uint2 gathers, 16-way parity (R14). R15: double-buffered staging (1 barrier
// per 128-edge chunk) and denominator folded into the final parity reduce
// (deletes the 8-barrier 256-tree). XCD half via blockIdx&7. ----
__global__ void __launch_bounds__(256) r15_agg3(
    const int* __restrict__ rs_dd, const uint* __restrict__ csr_dd, const uint* __restrict__ Hdd,
    float* __restrict__ agg_dd, int nd,
    const int* __restrict__ rs_dp, const uint* __restrict__ csr_dp, const uint* __restrict__ Hdp,
    float* __restrict__ agg_dp,
    const int* __restrict__ rs_cp, const uint* __restrict__ csr_cp, const uint* __restrict__ Hcp,
    float* __restrict__ agg_cp, int R)
{
    int b = blockIdx.x;
    int slot = b & 7;
    int half = slot >> 2;                    // XCDs 0-3 -> half 0, 4-7 -> half 1
    int row_g = (b >> 3) * 4 + (slot & 3);
    if (row_g >= R) return;                  // uniform (blockIdx only)
    const int* rs; const uint* csr; const uint* H2; float* out; int row;
    if (row_g < nd)          { rs = rs_dd; csr = csr_dd; H2 = Hdd; out = agg_dd; row = row_g; }
    else if (row_g < 2 * nd) { rs = rs_dp; csr = csr_dp; H2 = Hdp; out = agg_dp; row = row_g - nd; }
    else                     { rs = rs_cp; csr = csr_cp; H2 = Hcp; out = agg_cp; row = row_g - 2 * nd; }
    int t = threadIdx.x;
    int c2 = t & 15, g = t >> 4;             // uint2 word (4 ch), edge parity (16-way)
    int s = rs[row], e = rs[row + 1];

    __shared__ float se[2][128];
    __shared__ int ss[2][128];
    const uint2* Hh = (const uint2*)H2 + half * 16 + c2;
    float acc[4] = {0.f, 0.f, 0.f, 0.f};
    float dsum = 0.f;
    int nchunks = (e - s + 127) >> 7;

    // stage chunk 0
    if (nchunks > 0 && t < min(128, e - s)) {
        uint pk = csr[s + t];
        float wv = __uint_as_float((pk & 0xffffu) << 16);
        se[0][t] = wv; ss[0][t] = (int)(pk >> 16);
        dsum += wv;
    }
    __syncthreads();
    for (int kk = 0; kk < nchunks; kk++) {
        int pb = kk & 1;
        // stage next chunk into the other buffer (overlaps with gathers below)
        if (kk + 1 < nchunks) {
            int nb2 = s + (kk + 1) * 128;
            int nlim = min(128, e - nb2);
            if (t < nlim) {
                uint pk = csr[nb2 + t];
                float wv = __uint_as_float((pk & 0xffffu) << 16);
                se[pb ^ 1][t] = wv; ss[pb ^ 1][t] = (int)(pk >> 16);
                dsum += wv;
            }
        }
        int lim = min(128, e - s - kk * 128);
        if (lim == 128) {
#pragma unroll 8
            for (int jj = 0; jj < 8; jj++) {
                int j = jj * 16 + g;
                uint2 u = Hh[(size_t)ss[pb][j] * 32];
                float w = se[pb][j];
                acc[0] = fmaf(w, __uint_as_float(u.x << 16), acc[0]);
                acc[1] = fmaf(w, __uint_as_float(u.x & 0xffff0000u), acc[1]);
                acc[2] = fmaf(w, __uint_as_float(u.y << 16), acc[2]);
                acc[3] = fmaf(w, __uint_as_float(u.y & 0xffff0000u), acc[3]);
            }
        } else {
            for (int j = g; j < lim; j += 16) {
                uint2 u = Hh[(size_t)ss[pb][j] * 32];
                float w = se[pb][j];
                acc[0] = fmaf(w, __uint_as_float(u.x << 16), acc[0]);
                acc[1] = fmaf(w, __uint_as_float(u.x & 0xffff0000u), acc[1]);
                acc[2] = fmaf(w, __uint_as_float(u.y << 16), acc[2]);
                acc[3] = fmaf(w, __uint_as_float(u.y & 0xffff0000u), acc[3]);
            }
        }
        __syncthreads();
    }

    // denominator: full wave reduce, then 4 per-wave partials summed below
    float dwave = dsum;
#pragma unroll
    for (int off = 32; off > 0; off >>= 1) dwave += __shfl_xor(dwave, off, 64);
    // channel accumulators: combine the 4 in-wave parities
#pragma unroll
    for (int i = 0; i < 4; i++) {
        acc[i] += __shfl_xor(acc[i], 16, 64);
        acc[i] += __shfl_xor(acc[i], 32, 64);
    }
    __shared__ float rsum[4][64];
    __shared__ float dred[4];
    int w = t >> 6, l = t & 63;
    if (l == 0) dred[w] = dwave;
    if (l < 16) {
#pragma unroll
        for (int i = 0; i < 4; i++) rsum[w][l * 4 + i] = acc[i];
    }
    __syncthreads();
    if (t < 64) {
        float inv = 1.f / (dred[0] + dred[1] + dred[2] + dred[3] + 1e-16f);
        float v = rsum[0][t] + rsum[1][t] + rsum[2][t] + rsum[3][t];
        out[(size_t)row * HIDC + half * 64 + t] = v * inv;
    }
}

// ---- fused combine + relu + L2 normalize ----
__global__ void __launch_bounds__(128) r15_fuse(
    const float* __restrict__ agg_dd, const float* __restrict__ bias_dd,
    const float* __restrict__ agg_dp, const float* __restrict__ bias_dp,
    float* __restrict__ drugN, int nd,
    const float* __restrict__ agg_cp, const float* __restrict__ bias_cp,
    float* __restrict__ cellN)
{
    int b = blockIdx.x, c = threadIdx.x;
    float v;
    float* outN;
    int d;
    if (b < nd) {
        d = b;
        v = agg_dd[(size_t)d * HIDC + c] + bias_dd[c] + agg_dp[(size_t)d * HIDC + c] + bias_dp[c];
        outN = drugN;
    } else {
        d = b - nd;
        v = agg_cp[(size_t)d * HIDC + c] + bias_cp[c];
        outN = cellN;
    }
    v = fmaxf(v, 0.f);
    __shared__ float red[HIDC];
    red[c] = v * v; __syncthreads();
#pragma unroll
    for (int off = 64; off > 0; off >>= 1) { if (c < off) red[c] += red[c + off]; __syncthreads(); }
    float nrm = fmaxf(sqrtf(red[0]), 1e-12f);
    outN[(size_t)d * HIDC + c] = v / nrm;
}

// ---- hid gather -> bf16 ----
__global__ void __launch_bounds__(128) r15_gather_hid(
    const float* __restrict__ drugN, const float* __restrict__ cellN,
    const int* __restrict__ d1, const int* __restrict__ d2, const int* __restrict__ ce,
    short* __restrict__ hid)
{
    int b = blockIdx.x, c = threadIdx.x;
    hid[(size_t)b * 384 + c]       = f2b(drugN[(size_t)d1[b] * HIDC + c]);
    hid[(size_t)b * 384 + 128 + c] = f2b(drugN[(size_t)d2[b] * HIDC + c]);
    hid[(size_t)b * 384 + 256 + c] = f2b(cellN[(size_t)ce[b] * HIDC + c]);
}

// ---- bf16 MFMA GEMM: 128 x (NB*16) tile/block, 4 waves, BK=32 ----
template <int NB, int OUT_BF16>
__global__ void __launch_bounds__(256) r15_mgemm(
    const short* __restrict__ X, const short* __restrict__ Wt, const float* __restrict__ bias,
    void* __restrict__ Y, int M, int K, int N)
{
    constexpr int BN = NB * 16;
    __shared__ short As[128 * 40];
    __shared__ short Bs[BN * 40];
    int m0 = blockIdx.x * 128, n0 = blockIdx.y * BN;
    int tid = threadIdx.x;
    int w = tid >> 6, lane = tid & 63;
    int q = lane >> 4, t = lane & 15;
    int sr = tid >> 1, sc = tid & 1;

    floatx4 acc[2][NB];
#pragma unroll
    for (int i = 0; i < 2; i++)
#pragma unroll
        for (int c = 0; c < NB; c++) acc[i][c] = (floatx4){0.f, 0.f, 0.f, 0.f};

    for (int kt = 0; kt < K; kt += 32) {
        {
            const uint4* ga = (const uint4*)(X + (size_t)(m0 + sr) * K + kt + sc * 16);
            uint4 a0 = ga[0], a1 = ga[1];
            *(uint4*)&As[sr * 40 + sc * 16]     = a0;
            *(uint4*)&As[sr * 40 + sc * 16 + 8] = a1;
        }
        for (int tt = tid; tt < BN * 2; tt += 256) {
            int r = tt >> 1, h = tt & 1;
            const uint4* gb = (const uint4*)(Wt + (size_t)(n0 + r) * K + kt + h * 16);
            uint4 b0 = gb[0], b1 = gb[1];
            *(uint4*)&Bs[r * 40 + h * 16]     = b0;
            *(uint4*)&Bs[r * 40 + h * 16 + 8] = b1;
        }
        __syncthreads();
        short8 af[2], bf[NB];
#pragma unroll
        for (int i = 0; i < 2; i++)
            af[i] = *(const short8*)&As[(w * 32 + i * 16 + t) * 40 + q * 8];
#pragma unroll
        for (int c = 0; c < NB; c++)
            bf[c] = *(const short8*)&Bs[(c * 16 + t) * 40 + q * 8];
#pragma unroll
        for (int i = 0; i < 2; i++)
#pragma unroll
            for (int c = 0; c < NB; c++)
                acc[i][c] = __builtin_amdgcn_mfma_f32_16x16x32_bf16(af[i], bf[c], acc[i][c], 0, 0, 0);
        __syncthreads();
    }

    float bv[NB];
#pragma unroll
    for (int c = 0; c < NB; c++) bv[c] = bias[n0 + c * 16 + t];
#pragma unroll
    for (int i = 0; i < 2; i++) {
#pragma unroll
        for (int c = 0; c < NB; c++) {
#pragma unroll
            for (int ii = 0; ii < 4; ii++) {
                int m_g = m0 + w * 32 + i * 16 + q * 4 + ii;
                int n_g = n0 + c * 16 + t;
                float v = acc[i][c][ii] + bv[c];
                v = fmaxf(v, 0.f);
                if (OUT_BF16) ((short*)Y)[(size_t)m_g * N + n_g] = f2b(v);
                else          ((float*)Y)[(size_t)m_g * N + n_g] = v;
            }
        }
    }
}

// ---- final 256->2, wave per row, fp32 out ----
__global__ void __launch_bounds__(256) r15_final(
    const float* __restrict__ h2, const float* __restrict__ W3, const float* __restrict__ b3,
    float* __restrict__ out)
{
    int row = blockIdx.x * 4 + (threadIdx.x >> 6);
    int lane = threadIdx.x & 63;
    float a0 = 0.f, a1 = 0.f;
    for (int k = lane; k < 256; k += 64) {
        float h = h2[(size_t)row * 256 + k];
        a0 = fmaf(h, W3[k * 2 + 0], a0);
        a1 = fmaf(h, W3[k * 2 + 1], a1);
    }
#pragma unroll
    for (int off = 32; off > 0; off >>= 1) {
        a0 += __shfl_down(a0, off, 64);
        a1 += __shfl_down(a1, off, 64);
    }
    if (lane == 0) {
        out[row * 2 + 0] = a0 + b3[0];
        out[row * 2 + 1] = a1 + b3[1];
    }
}

extern "C" void kernel_launch(void* const* d_in, const int* in_sizes, int n_in,
                              void* d_out, int out_size, void* d_ws, size_t ws_size,
                              hipStream_t stream)
{
    const int* x_drug      = (const int*)d_in[0];
    const int* x_protein   = (const int*)d_in[1];
    const int* x_cell      = (const int*)d_in[2];
    const int* ei_dd       = (const int*)d_in[3];
    const float* attr_dd   = (const float*)d_in[4];
    const int* src_dp      = (const int*)d_in[5];
    const int* dst_dp      = (const int*)d_in[6];
    const int* src_cp      = (const int*)d_in[7];
    const int* dst_cp      = (const int*)d_in[8];
    const int* drug1       = (const int*)d_in[9];
    const int* drug2       = (const int*)d_in[10];
    const int* cellb       = (const int*)d_in[11];
    const float* drug_emb  = (const float*)d_in[12];
    const float* protein_emb = (const float*)d_in[13];
    const float* cell_emb  = (const float*)d_in[14];
    const float* W_dd      = (const float*)d_in[15];
    const float* a_src_dd  = (const float*)d_in[16];
    const float* a_dst_dd  = (const float*)d_in[17];
    const float* bias_dd   = (const float*)d_in[18];
    const float* W_edge_dd = (const float*)d_in[19];
    const float* a_edge_dd = (const float*)d_in[20];
    const float* W_dp      = (const float*)d_in[21];
    const float* a_src_dp  = (const float*)d_in[22];
    const float* a_dst_dp  = (const float*)d_in[23];
    const float* bias_dp   = (const float*)d_in[24];
    const float* W_cp      = (const float*)d_in[25];
    const float* a_src_cp  = (const float*)d_in[26];
    const float* a_dst_cp  = (const float*)d_in[27];
    const float* bias_cp   = (const float*)d_in[28];
    const float* W1        = (const float*)d_in[29];
    const float* b1        = (const float*)d_in[30];
    const float* W2        = (const float*)d_in[31];
    const float* b2        = (const float*)d_in[32];
    const float* W3        = (const float*)d_in[33];
    const float* b3        = (const float*)d_in[34];

    const int ND  = in_sizes[0];
    const int NPR = in_sizes[1];
    const int NCL = in_sizes[2];
    const int E_DD = in_sizes[4];
    const int E_DP = in_sizes[5];
    const int E_CP = in_sizes[7];
    const int B    = in_sizes[9];
    const int E_DD2 = E_DD + ND;

    // ---- carve workspace ----
    char* p = (char*)d_ws;
    auto carve = [&](size_t bytes) -> char* {
        char* r = p;
        p += (bytes + 255) & ~(size_t)255;
        return r;
    };
    // zeroed region
    char* zstart = p;
    int*   cnt_dd   = (int*)  carve((size_t)ND * 4);   // = deg after pass1
    float* attr_sum = (float*)carve((size_t)ND * 4);   // raw sums (scatter divides)
    int*   cnt_dp   = (int*)  carve((size_t)ND * 4);
    int*   cnt_cp   = (int*)  carve((size_t)NCL * 4);
    size_t zbytes = (size_t)(p - zstart);
    // non-zeroed
    int*   rs_dd    = (int*)  carve((size_t)(ND + 1) * 4);
    int*   rs_dp    = (int*)  carve((size_t)(ND + 1) * 4);
    int*   rs_cp    = (int*)  carve((size_t)(NCL + 1) * 4);
    float* c_edge   = (float*)carve(256);
    float* wa       = (float*)carve(6 * HIDC * 4);
    bf16*  H_dd     = (bf16*) carve((size_t)ND * HIDC * 2);
    bf16*  H_dp     = (bf16*) carve((size_t)NPR * HIDC * 2);
    bf16*  H_cp     = (bf16*) carve((size_t)NPR * HIDC * 2);
    float* ssrc_dd  = (float*)carve((size_t)ND * 4);
    float* sdst_dd  = (float*)carve((size_t)ND * 4);
    float* ssrc_dp  = (float*)carve((size_t)NPR * 4);
    float* sdst_dp  = (float*)carve((size_t)ND * 4);
    float* ssrc_cp  = (float*)carve((size_t)NPR * 4);
    float* sdst_cp  = (float*)carve((size_t)NCL * 4);
    int*   rank_dd  = (int*)  carve((size_t)E_DD * 4);
    int*   rank_dp  = (int*)  carve((size_t)E_DP * 4);
    int*   rank_cp  = (int*)  carve((size_t)E_CP * 4);
    uint*  csr_dd   = (uint*) carve((size_t)E_DD2 * 4);
    uint*  csr_dp   = (uint*) carve((size_t)E_DP * 4);
    uint*  csr_cp   = (uint*) carve((size_t)E_CP * 4);
    float* agg_dd   = (float*)carve((size_t)ND * HIDC * 4);
    float* agg_dp   = (float*)carve((size_t)ND * HIDC * 4);
    float* agg_cp   = (float*)carve((size_t)NCL * HIDC * 4);
    float* drugN    = (float*)carve((size_t)ND * HIDC * 4);
    float* cellN    = (float*)carve((size_t)NCL * HIDC * 4);
    short* hidb     = (short*)carve((size_t)B * 384 * 2);
    short* h1b      = (short*)carve((size_t)B * 768 * 2);
    float* h2       = (float*)carve((size_t)B * 256 * 4);
    short* Wt1      = (short*)carve((size_t)384 * 768 * 2);
    short* Wt2      = (short*)carve((size_t)768 * 256 * 2);

    auto cdiv = [](int a, int b) { return (a + b - 1) / b; };

    // ---- prep: zero + wa + weight transposes (one launch) ----
    int zwords = (int)(zbytes / 4);
    int nzb = cdiv(zwords, 256);
    int nT1 = (384 / 32) * (768 / 32);   // 288
    int nT2 = (768 / 32) * (256 / 32);   // 192
    r15_prep<<<nzb + 7 + nT1 + nT2, 256, 0, stream>>>(
        (int*)zstart, zwords, nzb,
        W_dd, W_dp, W_cp, a_src_dd, a_dst_dd, a_src_dp, a_dst_dp, a_src_cp, a_dst_cp,
        W_edge_dd, a_edge_dd, wa, c_edge, W1, Wt1, nT1, W2, Wt2);

    // ---- node GEMMs (fused) + attention scalars ----
    r15_node_gemm<<<ND / 16 + NPR / 16, 128, 0, stream>>>(
        drug_emb, x_drug, W_dd, H_dd, ND / 16,
        protein_emb, x_protein, W_dp, W_cp, H_dp, H_cp);
    r15_scalars<<<(ND + NPR + NCL) / 4, 256, 0, stream>>>(
        drug_emb, protein_emb, cell_emb, x_drug, x_protein, x_cell, wa,
        ssrc_dd, sdst_dd, sdst_dp, ssrc_dp, ssrc_cp, sdst_cp, ND, NPR, NCL);

    // ---- edge phase ----
    int nb_dd = cdiv(E_DD, CHUNK), nb_dp = cdiv(E_DP, CHUNK), nb_cp = cdiv(E_CP, CHUNK);
    r15_edge_pass1<<<nb_dd + nb_dp + nb_cp, 256, 0, stream>>>(
        ei_dd + E_DD, attr_dd, E_DD, nb_dd,
        dst_dp, E_DP, nb_dp,
        dst_cp, E_CP,
        ND, NCL,
        cnt_dd, attr_sum, cnt_dp, cnt_cp, rank_dd, rank_dp, rank_cp);
    r15_exscan3<<<3, 1024, 0, stream>>>(cnt_dd, rs_dd, ND, cnt_dp, rs_dp, ND, cnt_cp, rs_cp, NCL);
    r15_scatter<<<cdiv(E_DD + ND + E_DP + E_CP, 256), 256, 0, stream>>>(
        ei_dd, attr_dd, E_DD, ND, src_dp, dst_dp, E_DP, src_cp, dst_cp, E_CP,
        rank_dd, rank_dp, rank_cp, cnt_dd, attr_sum, c_edge,
        ssrc_dd, sdst_dd, ssrc_dp, sdst_dp, ssrc_cp, sdst_cp,
        rs_dd, rs_dp, rs_cp, csr_dd, csr_dp, csr_cp);

    // ---- softmax + aggregate (4 waves per (row,half), XCD-aware, dbuf) ----
    {
        int R = 2 * ND + NCL;
        int G = cdiv(R, 4) * 8;
        r15_agg3<<<G, 256, 0, stream>>>(
            rs_dd, csr_dd, (const uint*)H_dd, agg_dd, ND,
            rs_dp, csr_dp, (const uint*)H_dp, agg_dp,
            rs_cp, csr_cp, (const uint*)H_cp, agg_cp, R);
    }

    // ---- combine + relu + L2 normalize (fused) ----
    r15_fuse<<<ND + NCL, 128, 0, stream>>>(agg_dd, bias_dd, agg_dp, bias_dp, drugN, ND,
                                           agg_cp, bias_cp, cellN);

    // ---- batch gather + MLP (bf16 MFMA) ----
    r15_gather_hid<<<B, 128, 0, stream>>>(drugN, cellN, drug1, drug2, cellb, hidb);
    {
        dim3 g1(B / 128, 768 / 128);
        r15_mgemm<8, 1><<<g1, 256, 0, stream>>>(hidb, Wt1, b1, (void*)h1b, B, 384, 768);
        dim3 g2(B / 128, 256 / 64);
        r15_mgemm<4, 0><<<g2, 256, 0, stream>>>(h1b, Wt2, b2, (void*)h2, B, 768, 256);
    }
    r15_final<<<B / 4, 256, 0, stream>>>(h2, W3, b3, (float*)d_out);
}

// Round 16
// 316.766 us; speedup vs baseline: 1.0889x; 1.0889x over previous
//
#include <hip/hip_runtime.h>
#include <hip/hip_bf16.h>

// FP32 tensors on device (R2). H tables bf16 (R4). MLP via bf16 MFMA (R5).
// Edge: rank-array pass1 + simple scatter (R13). Packed 4B CSR (R9/R10).
// Agg: 4-wave (row,half), XCD half-split, uint2, dbuf (R12-R15) — measured
// plateau ~53us across 3 variants (L2 random-gather bound; leave alone).
// R16: front-end mega-fusion. K0 = zero+wa (dependency roots). K1 = pass1 |
// node_gemm(256thr/32rows) | cvtT | scalars in ONE launch (independent given
// K0; previously ~75us serial). 12 -> 10 launches.
#define HIDC 128
typedef __hip_bfloat16 bf16;
typedef __attribute__((ext_vector_type(8))) short short8;   // 8 bf16 (4 VGPR)
typedef __attribute__((ext_vector_type(4))) float floatx4;  // 4 fp32 acc

#define CHUNK 4096   // edges per pass1 block

__device__ __forceinline__ short f2b(float f) {
    unsigned int u = __builtin_bit_cast(unsigned int, f);
    u += 0x7fff + ((u >> 16) & 1);          // RNE
    return (short)(u >> 16);
}

__device__ __forceinline__ uint packe(int s, float ev) {
    float w = __expf(ev);                    // exp > 0, |logit| <= ~9 -> bf16-safe
    return ((uint)s << 16) | (uint)(unsigned short)f2b(w);
}

// ---- K0: zero counters | wa = W@a | c_edge ----
__global__ void __launch_bounds__(256) r16_pre(
    int* __restrict__ zptr, int zwords, int nzb,
    const float* __restrict__ W_dd, const float* __restrict__ W_dp, const float* __restrict__ W_cp,
    const float* __restrict__ a0, const float* __restrict__ a1, const float* __restrict__ a2,
    const float* __restrict__ a3, const float* __restrict__ a4, const float* __restrict__ a5,
    const float* __restrict__ W_edge, const float* __restrict__ a_edge,
    float* __restrict__ wa, float* __restrict__ c_edge)
{
    int b = blockIdx.x;
    int tid = threadIdx.x;
    if (b < nzb) {
        int i = b * 256 + tid;
        if (i < zwords) zptr[i] = 0;
        return;
    }
    b -= nzb;
    __shared__ float as[HIDC];
    int k = tid;
    if (b < 6) {
        const float* W = (b < 2) ? W_dd : (b < 4) ? W_dp : W_cp;
        const float* a = (b == 0) ? a0 : (b == 1) ? a1 : (b == 2) ? a2 : (b == 3) ? a3 : (b == 4) ? a4 : a5;
        if (k < HIDC) as[k] = a[k];
        __syncthreads();
        if (k < HIDC) {
            float s = 0.f;
#pragma unroll 8
            for (int c = 0; c < HIDC; c++) s = fmaf(W[k * HIDC + c], as[c], s);
            wa[b * HIDC + k] = s;
        }
    } else {
        if (k < HIDC) as[k] = W_edge[k] * a_edge[k];
        __syncthreads();
#pragma unroll
        for (int off = 64; off > 0; off >>= 1) { if (k < off) as[k] += as[k + off]; __syncthreads(); }
        if (k == 0) c_edge[0] = as[0];
    }
}

// ---- K1 mega: [pass1 blocks][node_gemm blocks][cvtT blocks][scalars blocks] ----
// 32 KB shared LDS union; each block takes exactly one branch (blockIdx-uniform).
__global__ void __launch_bounds__(256) r16_mega(
    // pass1
    const int* __restrict__ dst_dd, const float* __restrict__ attr_dd, int E_dd, int nb_dd,
    const int* __restrict__ dst_dp, int E_dp, int nb_dp,
    const int* __restrict__ dst_cp, int E_cp, int nb_cp,
    int nd, int ncl,
    int* __restrict__ cnt_dd, float* __restrict__ attr_sum,
    int* __restrict__ cnt_dp, int* __restrict__ cnt_cp,
    int* __restrict__ rank_dd, int* __restrict__ rank_dp, int* __restrict__ rank_cp,
    // node gemm (32 rows / block)
    const float* __restrict__ drug_emb, const int* __restrict__ x_drug,
    const float* __restrict__ W_dd, bf16* __restrict__ H_dd, int ndb32,
    const float* __restrict__ prot_emb, const int* __restrict__ x_prot,
    const float* __restrict__ W_dp, const float* __restrict__ W_cp,
    bf16* __restrict__ H_dp, bf16* __restrict__ H_cp, int npb32,
    // cvtT
    const float* __restrict__ W1, short* __restrict__ Wt1, int nT1,
    const float* __restrict__ W2, short* __restrict__ Wt2, int nT2,
    // scalars
    const float* __restrict__ cell_emb, const int* __restrict__ x_cell,
    const float* __restrict__ wa,
    float* __restrict__ ssrc_dd, float* __restrict__ sdst_dd, float* __restrict__ sdst_dp,
    float* __restrict__ ssrc_dp, float* __restrict__ ssrc_cp, float* __restrict__ sdst_cp,
    int npr)
{
    __shared__ int smem[8192];               // 32 KB union
    int b = blockIdx.x;
    int tid = threadIdx.x;
    int nb_pass = nb_dd + nb_dp + nb_cp;

    if (b < nb_pass) {
        // ---------------- pass1 (R13-verified) ----------------
        int* lcnt = smem;
        float* lattr = (float*)(smem + 4096);
        const int* dst; const float* attr = nullptr; int E, e0, bins;
        int* gcnt; int* rank;
        if (b < nb_dd) {
            dst = dst_dd; attr = attr_dd; E = E_dd; e0 = b * CHUNK; bins = nd;
            gcnt = cnt_dd; rank = rank_dd;
        } else if (b < nb_dd + nb_dp) {
            dst = dst_dp; E = E_dp; e0 = (b - nb_dd) * CHUNK; bins = nd;
            gcnt = cnt_dp; rank = rank_dp;
        } else {
            dst = dst_cp; E = E_cp; e0 = (b - nb_dd - nb_dp) * CHUNK; bins = ncl;
            gcnt = cnt_cp; rank = rank_cp;
        }
        for (int bb = tid; bb < bins; bb += 256) { lcnt[bb] = 0; if (attr) lattr[bb] = 0.f; }
        __syncthreads();
        int e1 = min(e0 + CHUNK, E);
        for (int i = e0 + tid; i < e1; i += 256) {
            int d = dst[i];
            rank[i] = atomicAdd(&lcnt[d], 1);
            if (attr) atomicAdd(&lattr[d], attr[i]);
        }
        __syncthreads();
        for (int bb = tid; bb < bins; bb += 256) {
            int c = lcnt[bb];
            if (c > 0) {
                lcnt[bb] = atomicAdd(&gcnt[bb], c);
                if (attr) atomicAdd(&attr_sum[bb], lattr[bb]);
            }
        }
        __syncthreads();
        for (int i = e0 + tid; i < e1; i += 256) {
            rank[i] += lcnt[dst[i]];
        }
        return;
    }
    b -= nb_pass;

    if (b < ndb32 + npb32) {
        // ---------------- node GEMM: 32 rows / 256 threads ----------------
        int* ids = smem;
        float* xs = (float*)(smem + 32);     // 32 rows x 128 = 16 KB
        bool isdrug = b < ndb32;
        int r0 = (isdrug ? b : b - ndb32) * 32;
        const float* emb = isdrug ? drug_emb : prot_emb;
        const int* idx = isdrug ? x_drug : x_prot;
        if (tid < 32) ids[tid] = idx[r0 + tid];
        __syncthreads();
        for (int t = tid; t < 32 * HIDC; t += 256) {
            int r = t >> 7, k = t & 127;
            xs[t] = emb[(size_t)ids[r] * HIDC + k];
        }
        __syncthreads();
        int c = tid & 127, h = tid >> 7;     // column, row-half
        const float* xb = xs + (h * 16) * HIDC;
        int rbase = r0 + h * 16;
        if (isdrug) {
            float acc[16];
#pragma unroll
            for (int r = 0; r < 16; r++) acc[r] = 0.f;
            for (int k = 0; k < HIDC; k += 4) {
                float w0 = W_dd[(k + 0) * HIDC + c];
                float w1 = W_dd[(k + 1) * HIDC + c];
                float w2 = W_dd[(k + 2) * HIDC + c];
                float w3 = W_dd[(k + 3) * HIDC + c];
#pragma unroll
                for (int r = 0; r < 16; r++) {
                    float4 x = *(const float4*)&xb[r * HIDC + k];
                    acc[r] = fmaf(x.x, w0, fmaf(x.y, w1, fmaf(x.z, w2, fmaf(x.w, w3, acc[r]))));
                }
            }
#pragma unroll
            for (int r = 0; r < 16; r++)
                H_dd[(size_t)(rbase + r) * HIDC + c] = __float2bfloat16(acc[r]);
        } else {
            float accA[16], accB[16];
#pragma unroll
            for (int r = 0; r < 16; r++) { accA[r] = 0.f; accB[r] = 0.f; }
            for (int k = 0; k < HIDC; k += 2) {
                float a0 = W_dp[(k + 0) * HIDC + c];
                float a1 = W_dp[(k + 1) * HIDC + c];
                float b0 = W_cp[(k + 0) * HIDC + c];
                float b1 = W_cp[(k + 1) * HIDC + c];
#pragma unroll
                for (int r = 0; r < 16; r++) {
                    float2 x = *(const float2*)&xb[r * HIDC + k];
                    accA[r] = fmaf(x.x, a0, fmaf(x.y, a1, accA[r]));
                    accB[r] = fmaf(x.x, b0, fmaf(x.y, b1, accB[r]));
                }
            }
#pragma unroll
            for (int r = 0; r < 16; r++) {
                H_dp[(size_t)(rbase + r) * HIDC + c] = __float2bfloat16(accA[r]);
                H_cp[(size_t)(rbase + r) * HIDC + c] = __float2bfloat16(accB[r]);
            }
        }
        return;
    }
    b -= ndb32 + npb32;

    if (b < nT1 + nT2) {
        // ---------------- W -> bf16 transposed ----------------
        short* T = (short*)smem;             // 32*34 shorts
        const float* W; short* Wt; int K, N, k0, n0;
        if (b < nT1) { W = W1; Wt = Wt1; K = 384; N = 768; k0 = (b / 24) * 32; n0 = (b % 24) * 32; }
        else { b -= nT1; W = W2; Wt = Wt2; K = 768; N = 256; k0 = (b / 8) * 32; n0 = (b % 8) * 32; }
        int cc = tid & 31, rr = tid >> 5;
#pragma unroll
        for (int it = 0; it < 4; it++) {
            int r = it * 8 + rr;
            T[r * 34 + cc] = f2b(W[(size_t)(k0 + r) * N + n0 + cc]);
        }
        __syncthreads();
#pragma unroll
        for (int it = 0; it < 4; it++) {
            int r = it * 8 + rr;
            Wt[(size_t)(n0 + r) * K + k0 + cc] = T[cc * 34 + r];
        }
        return;
    }
    b -= nT1 + nT2;

    // ---------------- attention scalars ----------------
    {
        int g = b * 4 + (tid >> 6);
        int l = tid & 63;
        const float2* wa2 = (const float2*)wa;
        if (g < nd) {
            int id = x_drug[g];
            float2 e = ((const float2*)drug_emb)[(size_t)id * 64 + l];
            float2 w0 = wa2[0 * 64 + l], w1 = wa2[1 * 64 + l], w3 = wa2[3 * 64 + l];
            float p0 = e.x * w0.x + e.y * w0.y;
            float p1 = e.x * w1.x + e.y * w1.y;
            float p2 = e.x * w3.x + e.y * w3.y;
#pragma unroll
            for (int off = 32; off > 0; off >>= 1) {
                p0 += __shfl_xor(p0, off, 64);
                p1 += __shfl_xor(p1, off, 64);
                p2 += __shfl_xor(p2, off, 64);
            }
            if (l == 0) { ssrc_dd[g] = p0; sdst_dd[g] = p1; sdst_dp[g] = p2; }
        } else if (g < nd + npr) {
            int r = g - nd;
            int id = x_prot[r];
            float2 e = ((const float2*)prot_emb)[(size_t)id * 64 + l];
            float2 w2 = wa2[2 * 64 + l], w4 = wa2[4 * 64 + l];
            float p0 = e.x * w2.x + e.y * w2.y;
            float p1 = e.x * w4.x + e.y * w4.y;
#pragma unroll
            for (int off = 32; off > 0; off >>= 1) {
                p0 += __shfl_xor(p0, off, 64);
                p1 += __shfl_xor(p1, off, 64);
            }
            if (l == 0) { ssrc_dp[r] = p0; ssrc_cp[r] = p1; }
        } else if (g < nd + npr + ncl) {
            int r = g - nd - npr;
            int id = x_cell[r];
            float2 e = ((const float2*)cell_emb)[(size_t)id * 64 + l];
            float2 w5 = wa2[5 * 64 + l];
            float p0 = e.x * w5.x + e.y * w5.y;
#pragma unroll
            for (int off = 32; off > 0; off >>= 1) p0 += __shfl_xor(p0, off, 64);
            if (l == 0) sdst_cp[r] = p0;
        }
    }
}

// ---- three exclusive scans; scan 0 adds +1/elem (dd self-loops) ----
__global__ void __launch_bounds__(1024) r16_exscan3(
    const int* __restrict__ in0, int* __restrict__ out0, int n0,
    const int* __restrict__ in1, int* __restrict__ out1, int n1,
    const int* __restrict__ in2, int* __restrict__ out2, int n2)
{
    const int* in; int* out; int n; int inc;
    if (blockIdx.x == 0)      { in = in0; out = out0; n = n0; inc = 1; }
    else if (blockIdx.x == 1) { in = in1; out = out1; n = n1; inc = 0; }
    else                      { in = in2; out = out2; n = n2; inc = 0; }
    __shared__ int buf[1024];
    __shared__ int carry;
    int tid = threadIdx.x;
    if (tid == 0) carry = 0;
    __syncthreads();
    for (int base = 0; base < n; base += 1024) {
        int i = base + tid;
        int v = (i < n) ? (in[i] + inc) : 0;
        buf[tid] = v; __syncthreads();
        for (int off = 1; off < 1024; off <<= 1) {
            int t = (tid >= off) ? buf[tid - off] : 0;
            __syncthreads();
            buf[tid] += t;
            __syncthreads();
        }
        int c0 = carry;
        int incl = buf[tid];
        if (i < n) out[i] = c0 + incl - v;
        __syncthreads();
        if (tid == 1023) carry = c0 + buf[1023];
        __syncthreads();
    }
    if (tid == 0) out[n] = carry;
}

// ---- scatter into packed CSR, no atomics (slot = rs[d]+rank) ----
__global__ void r16_scatter(
    const int* __restrict__ ei_dd, const float* __restrict__ attr_dd, int E_dd, int nd,
    const int* __restrict__ src_dp, const int* __restrict__ dst_dp, int E_dp,
    const int* __restrict__ src_cp, const int* __restrict__ dst_cp, int E_cp,
    const int* __restrict__ rank_dd, const int* __restrict__ rank_dp, const int* __restrict__ rank_cp,
    const int* __restrict__ deg_dd, const float* __restrict__ attr_sum,
    const float* __restrict__ c_edge_ptr,
    const float* __restrict__ ssrc_dd, const float* __restrict__ sdst_dd,
    const float* __restrict__ ssrc_dp, const float* __restrict__ sdst_dp,
    const float* __restrict__ ssrc_cp, const float* __restrict__ sdst_cp,
    const int* __restrict__ rs_dd, const int* __restrict__ rs_dp, const int* __restrict__ rs_cp,
    uint* __restrict__ csr_dd, uint* __restrict__ csr_dp, uint* __restrict__ csr_cp)
{
    int i = blockIdx.x * 256 + threadIdx.x;
    if (i < E_dd) {
        int s = ei_dd[i], d = ei_dd[E_dd + i];
        float ev = ssrc_dd[s] + sdst_dd[d] + attr_dd[i] * c_edge_ptr[0];
        ev = (ev > 0.f) ? ev : 0.2f * ev;
        csr_dd[rs_dd[d] + rank_dd[i]] = packe(s, ev);
        return;
    }
    i -= E_dd;
    if (i < nd) {   // dd self-loops with mean-attr fill
        int d = i;
        int dg = deg_dd[d];
        float mean = attr_sum[d] / fmaxf((float)dg, 1.0f);
        float ev = ssrc_dd[d] + sdst_dd[d] + mean * c_edge_ptr[0];
        ev = (ev > 0.f) ? ev : 0.2f * ev;
        csr_dd[rs_dd[d] + dg] = packe(d, ev);
        return;
    }
    i -= nd;
    if (i < E_dp) {
        int d = dst_dp[i], s = src_dp[i];
        float ev = ssrc_dp[s] + sdst_dp[d];
        ev = (ev > 0.f) ? ev : 0.2f * ev;
        csr_dp[rs_dp[d] + rank_dp[i]] = packe(s, ev);
        return;
    }
    i -= E_dp;
    if (i < E_cp) {
        int d = dst_cp[i], s = src_cp[i];
        float ev = ssrc_cp[s] + sdst_cp[d];
        ev = (ev > 0.f) ? ev : 0.2f * ev;
        csr_cp[rs_cp[d] + rank_cp[i]] = packe(s, ev);
    }
}

// ---- softmax+aggregate (R15-verified; measured plateau ~53us) ----
__global__ void __launch_bounds__(256) r16_agg3(
    const int* __restrict__ rs_dd, const uint* __restrict__ csr_dd, const uint* __restrict__ Hdd,
    float* __restrict__ agg_dd, int nd,
    const int* __restrict__ rs_dp, const uint* __restrict__ csr_dp, const uint* __restrict__ Hdp,
    float* __restrict__ agg_dp,
    const int* __restrict__ rs_cp, const uint* __restrict__ csr_cp, const uint* __restrict__ Hcp,
    float* __restrict__ agg_cp, int R)
{
    int b = blockIdx.x;
    int slot = b & 7;
    int half = slot >> 2;
    int row_g = (b >> 3) * 4 + (slot & 3);
    if (row_g >= R) return;
    const int* rs; const uint* csr; const uint* H2; float* out; int row;
    if (row_g < nd)          { rs = rs_dd; csr = csr_dd; H2 = Hdd; out = agg_dd; row = row_g; }
    else if (row_g < 2 * nd) { rs = rs_dp; csr = csr_dp; H2 = Hdp; out = agg_dp; row = row_g - nd; }
    else                     { rs = rs_cp; csr = csr_cp; H2 = Hcp; out = agg_cp; row = row_g - 2 * nd; }
    int t = threadIdx.x;
    int c2 = t & 15, g = t >> 4;
    int s = rs[row], e = rs[row + 1];

    __shared__ float se[2][128];
    __shared__ int ss[2][128];
    const uint2* Hh = (const uint2*)H2 + half * 16 + c2;
    float acc[4] = {0.f, 0.f, 0.f, 0.f};
    float dsum = 0.f;
    int nchunks = (e - s + 127) >> 7;

    if (nchunks > 0 && t < min(128, e - s)) {
        uint pk = csr[s + t];
        float wv = __uint_as_float((pk & 0xffffu) << 16);
        se[0][t] = wv; ss[0][t] = (int)(pk >> 16);
        dsum += wv;
    }
    __syncthreads();
    for (int kk = 0; kk < nchunks; kk++) {
        int pb = kk & 1;
        if (kk + 1 < nchunks) {
            int nb2 = s + (kk + 1) * 128;
            int nlim = min(128, e - nb2);
            if (t < nlim) {
                uint pk = csr[nb2 + t];
                float wv = __uint_as_float((pk & 0xffffu) << 16);
                se[pb ^ 1][t] = wv; ss[pb ^ 1][t] = (int)(pk >> 16);
                dsum += wv;
            }
        }
        int lim = min(128, e - s - kk * 128);
        if (lim == 128) {
#pragma unroll 8
            for (int jj = 0; jj < 8; jj++) {
                int j = jj * 16 + g;
                uint2 u = Hh[(size_t)ss[pb][j] * 32];
                float w = se[pb][j];
                acc[0] = fmaf(w, __uint_as_float(u.x << 16), acc[0]);
                acc[1] = fmaf(w, __uint_as_float(u.x & 0xffff0000u), acc[1]);
                acc[2] = fmaf(w, __uint_as_float(u.y << 16), acc[2]);
                acc[3] = fmaf(w, __uint_as_float(u.y & 0xffff0000u), acc[3]);
            }
        } else {
            for (int j = g; j < lim; j += 16) {
                uint2 u = Hh[(size_t)ss[pb][j] * 32];
                float w = se[pb][j];
                acc[0] = fmaf(w, __uint_as_float(u.x << 16), acc[0]);
                acc[1] = fmaf(w, __uint_as_float(u.x & 0xffff0000u), acc[1]);
                acc[2] = fmaf(w, __uint_as_float(u.y << 16), acc[2]);
                acc[3] = fmaf(w, __uint_as_float(u.y & 0xffff0000u), acc[3]);
            }
        }
        __syncthreads();
    }

    float dwave = dsum;
#pragma unroll
    for (int off = 32; off > 0; off >>= 1) dwave += __shfl_xor(dwave, off, 64);
#pragma unroll
    for (int i = 0; i < 4; i++) {
        acc[i] += __shfl_xor(acc[i], 16, 64);
        acc[i] += __shfl_xor(acc[i], 32, 64);
    }
    __shared__ float rsum[4][64];
    __shared__ float dred[4];
    int w = t >> 6, l = t & 63;
    if (l == 0) dred[w] = dwave;
    if (l < 16) {
#pragma unroll
        for (int i = 0; i < 4; i++) rsum[w][l * 4 + i] = acc[i];
    }
    __syncthreads();
    if (t < 64) {
        float inv = 1.f / (dred[0] + dred[1] + dred[2] + dred[3] + 1e-16f);
        float v = rsum[0][t] + rsum[1][t] + rsum[2][t] + rsum[3][t];
        out[(size_t)row * HIDC + half * 64 + t] = v * inv;
    }
}

// ---- fused combine + relu + L2 normalize ----
__global__ void __launch_bounds__(128) r16_fuse(
    const float* __restrict__ agg_dd, const float* __restrict__ bias_dd,
    const float* __restrict__ agg_dp, const float* __restrict__ bias_dp,
    float* __restrict__ drugN, int nd,
    const float* __restrict__ agg_cp, const float* __restrict__ bias_cp,
    float* __restrict__ cellN)
{
    int b = blockIdx.x, c = threadIdx.x;
    float v;
    float* outN;
    int d;
    if (b < nd) {
        d = b;
        v = agg_dd[(size_t)d * HIDC + c] + bias_dd[c] + agg_dp[(size_t)d * HIDC + c] + bias_dp[c];
        outN = drugN;
    } else {
        d = b - nd;
        v = agg_cp[(size_t)d * HIDC + c] + bias_cp[c];
        outN = cellN;
    }
    v = fmaxf(v, 0.f);
    __shared__ float red[HIDC];
    red[c] = v * v; __syncthreads();
#pragma unroll
    for (int off = 64; off > 0; off >>= 1) { if (c < off) red[c] += red[c + off]; __syncthreads(); }
    float nrm = fmaxf(sqrtf(red[0]), 1e-12f);
    outN[(size_t)d * HIDC + c] = v / nrm;
}

// ---- hid gather -> bf16 ----
__global__ void __launch_bounds__(128) r16_gather_hid(
    const float* __restrict__ drugN, const float* __restrict__ cellN,
    const int* __restrict__ d1, const int* __restrict__ d2, const int* __restrict__ ce,
    short* __restrict__ hid)
{
    int b = blockIdx.x, c = threadIdx.x;
    hid[(size_t)b * 384 + c]       = f2b(drugN[(size_t)d1[b] * HIDC + c]);
    hid[(size_t)b * 384 + 128 + c] = f2b(drugN[(size_t)d2[b] * HIDC + c]);
    hid[(size_t)b * 384 + 256 + c] = f2b(cellN[(size_t)ce[b] * HIDC + c]);
}

// ---- bf16 MFMA GEMM: 128 x (NB*16) tile/block, 4 waves, BK=32 ----
template <int NB, int OUT_BF16>
__global__ void __launch_bounds__(256) r16_mgemm(
    const short* __restrict__ X, const short* __restrict__ Wt, const float* __restrict__ bias,
    void* __restrict__ Y, int M, int K, int N)
{
    constexpr int BN = NB * 16;
    __shared__ short As[128 * 40];
    __shared__ short Bs[BN * 40];
    int m0 = blockIdx.x * 128, n0 = blockIdx.y * BN;
    int tid = threadIdx.x;
    int w = tid >> 6, lane = tid & 63;
    int q = lane >> 4, t = lane & 15;
    int sr = tid >> 1, sc = tid & 1;

    floatx4 acc[2][NB];
#pragma unroll
    for (int i = 0; i < 2; i++)
#pragma unroll
        for (int c = 0; c < NB; c++) acc[i][c] = (floatx4){0.f, 0.f, 0.f, 0.f};

    for (int kt = 0; kt < K; kt += 32) {
        {
            const uint4* ga = (const uint4*)(X + (size_t)(m0 + sr) * K + kt + sc * 16);
            uint4 a0 = ga[0], a1 = ga[1];
            *(uint4*)&As[sr * 40 + sc * 16]     = a0;
            *(uint4*)&As[sr * 40 + sc * 16 + 8] = a1;
        }
        for (int tt = tid; tt < BN * 2; tt += 256) {
            int r = tt >> 1, h = tt & 1;
            const uint4* gb = (const uint4*)(Wt + (size_t)(n0 + r) * K + kt + h * 16);
            uint4 b0 = gb[0], b1 = gb[1];
            *(uint4*)&Bs[r * 40 + h * 16]     = b0;
            *(uint4*)&Bs[r * 40 + h * 16 + 8] = b1;
        }
        __syncthreads();
        short8 af[2], bf[NB];
#pragma unroll
        for (int i = 0; i < 2; i++)
            af[i] = *(const short8*)&As[(w * 32 + i * 16 + t) * 40 + q * 8];
#pragma unroll
        for (int c = 0; c < NB; c++)
            bf[c] = *(const short8*)&Bs[(c * 16 + t) * 40 + q * 8];
#pragma unroll
        for (int i = 0; i < 2; i++)
#pragma unroll
            for (int c = 0; c < NB; c++)
                acc[i][c] = __builtin_amdgcn_mfma_f32_16x16x32_bf16(af[i], bf[c], acc[i][c], 0, 0, 0);
        __syncthreads();
    }

    float bv[NB];
#pragma unroll
    for (int c = 0; c < NB; c++) bv[c] = bias[n0 + c * 16 + t];
#pragma unroll
    for (int i = 0; i < 2; i++) {
#pragma unroll
        for (int c = 0; c < NB; c++) {
#pragma unroll
            for (int ii = 0; ii < 4; ii++) {
                int m_g = m0 + w * 32 + i * 16 + q * 4 + ii;
                int n_g = n0 + c * 16 + t;
                float v = acc[i][c][ii] + bv[c];
                v = fmaxf(v, 0.f);
                if (OUT_BF16) ((short*)Y)[(size_t)m_g * N + n_g] = f2b(v);
                else          ((float*)Y)[(size_t)m_g * N + n_g] = v;
            }
        }
    }
}

// ---- final 256->2, wave per row, fp32 out ----
__global__ void __launch_bounds__(256) r16_final(
    const float* __restrict__ h2, const float* __restrict__ W3, const float* __restrict__ b3,
    float* __restrict__ out)
{
    int row = blockIdx.x * 4 + (threadIdx.x >> 6);
    int lane = threadIdx.x & 63;
    float a0 = 0.f, a1 = 0.f;
    for (int k = lane; k < 256; k += 64) {
        float h = h2[(size_t)row * 256 + k];
        a0 = fmaf(h, W3[k * 2 + 0], a0);
        a1 = fmaf(h, W3[k * 2 + 1], a1);
    }
#pragma unroll
    for (int off = 32; off > 0; off >>= 1) {
        a0 += __shfl_down(a0, off, 64);
        a1 += __shfl_down(a1, off, 64);
    }
    if (lane == 0) {
        out[row * 2 + 0] = a0 + b3[0];
        out[row * 2 + 1] = a1 + b3[1];
    }
}

extern "C" void kernel_launch(void* const* d_in, const int* in_sizes, int n_in,
                              void* d_out, int out_size, void* d_ws, size_t ws_size,
                              hipStream_t stream)
{
    const int* x_drug      = (const int*)d_in[0];
    const int* x_protein   = (const int*)d_in[1];
    const int* x_cell      = (const int*)d_in[2];
    const int* ei_dd       = (const int*)d_in[3];
    const float* attr_dd   = (const float*)d_in[4];
    const int* src_dp      = (const int*)d_in[5];
    const int* dst_dp      = (const int*)d_in[6];
    const int* src_cp      = (const int*)d_in[7];
    const int* dst_cp      = (const int*)d_in[8];
    const int* drug1       = (const int*)d_in[9];
    const int* drug2       = (const int*)d_in[10];
    const int* cellb       = (const int*)d_in[11];
    const float* drug_emb  = (const float*)d_in[12];
    const float* protein_emb = (const float*)d_in[13];
    const float* cell_emb  = (const float*)d_in[14];
    const float* W_dd      = (const float*)d_in[15];
    const float* a_src_dd  = (const float*)d_in[16];
    const float* a_dst_dd  = (const float*)d_in[17];
    const float* bias_dd   = (const float*)d_in[18];
    const float* W_edge_dd = (const float*)d_in[19];
    const float* a_edge_dd = (const float*)d_in[20];
    const float* W_dp      = (const float*)d_in[21];
    const float* a_src_dp  = (const float*)d_in[22];
    const float* a_dst_dp  = (const float*)d_in[23];
    const float* bias_dp   = (const float*)d_in[24];
    const float* W_cp      = (const float*)d_in[25];
    const float* a_src_cp  = (const float*)d_in[26];
    const float* a_dst_cp  = (const float*)d_in[27];
    const float* bias_cp   = (const float*)d_in[28];
    const float* W1        = (const float*)d_in[29];
    const float* b1        = (const float*)d_in[30];
    const float* W2        = (const float*)d_in[31];
    const float* b2        = (const float*)d_in[32];
    const float* W3        = (const float*)d_in[33];
    const float* b3        = (const float*)d_in[34];

    const int ND  = in_sizes[0];
    const int NPR = in_sizes[1];
    const int NCL = in_sizes[2];
    const int E_DD = in_sizes[4];
    const int E_DP = in_sizes[5];
    const int E_CP = in_sizes[7];
    const int B    = in_sizes[9];
    const int E_DD2 = E_DD + ND;

    // ---- carve workspace ----
    char* p = (char*)d_ws;
    auto carve = [&](size_t bytes) -> char* {
        char* r = p;
        p += (bytes + 255) & ~(size_t)255;
        return r;
    };
    // zeroed region
    char* zstart = p;
    int*   cnt_dd   = (int*)  carve((size_t)ND * 4);   // = deg after pass1
    float* attr_sum = (float*)carve((size_t)ND * 4);   // raw sums (scatter divides)
    int*   cnt_dp   = (int*)  carve((size_t)ND * 4);
    int*   cnt_cp   = (int*)  carve((size_t)NCL * 4);
    size_t zbytes = (size_t)(p - zstart);
    // non-zeroed
    int*   rs_dd    = (int*)  carve((size_t)(ND + 1) * 4);
    int*   rs_dp    = (int*)  carve((size_t)(ND + 1) * 4);
    int*   rs_cp    = (int*)  carve((size_t)(NCL + 1) * 4);
    float* c_edge   = (float*)carve(256);
    float* wa       = (float*)carve(6 * HIDC * 4);
    bf16*  H_dd     = (bf16*) carve((size_t)ND * HIDC * 2);
    bf16*  H_dp     = (bf16*) carve((size_t)NPR * HIDC * 2);
    bf16*  H_cp     = (bf16*) carve((size_t)NPR * HIDC * 2);
    float* ssrc_dd  = (float*)carve((size_t)ND * 4);
    float* sdst_dd  = (float*)carve((size_t)ND * 4);
    float* ssrc_dp  = (float*)carve((size_t)NPR * 4);
    float* sdst_dp  = (float*)carve((size_t)ND * 4);
    float* ssrc_cp  = (float*)carve((size_t)NPR * 4);
    float* sdst_cp  = (float*)carve((size_t)NCL * 4);
    int*   rank_dd  = (int*)  carve((size_t)E_DD * 4);
    int*   rank_dp  = (int*)  carve((size_t)E_DP * 4);
    int*   rank_cp  = (int*)  carve((size_t)E_CP * 4);
    uint*  csr_dd   = (uint*) carve((size_t)E_DD2 * 4);
    uint*  csr_dp   = (uint*) carve((size_t)E_DP * 4);
    uint*  csr_cp   = (uint*) carve((size_t)E_CP * 4);
    float* agg_dd   = (float*)carve((size_t)ND * HIDC * 4);
    float* agg_dp   = (float*)carve((size_t)ND * HIDC * 4);
    float* agg_cp   = (float*)carve((size_t)NCL * HIDC * 4);
    float* drugN    = (float*)carve((size_t)ND * HIDC * 4);
    float* cellN    = (float*)carve((size_t)NCL * HIDC * 4);
    short* hidb     = (short*)carve((size_t)B * 384 * 2);
    short* h1b      = (short*)carve((size_t)B * 768 * 2);
    float* h2       = (float*)carve((size_t)B * 256 * 4);
    short* Wt1      = (short*)carve((size_t)384 * 768 * 2);
    short* Wt2      = (short*)carve((size_t)768 * 256 * 2);

    auto cdiv = [](int a, int b) { return (a + b - 1) / b; };

    // ---- K0: zero + wa + c_edge ----
    int zwords = (int)(zbytes / 4);
    int nzb = cdiv(zwords, 256);
    r16_pre<<<nzb + 7, 256, 0, stream>>>(
        (int*)zstart, zwords, nzb,
        W_dd, W_dp, W_cp, a_src_dd, a_dst_dd, a_src_dp, a_dst_dp, a_src_cp, a_dst_cp,
        W_edge_dd, a_edge_dd, wa, c_edge);

    // ---- K1: mega (pass1 | node GEMM | cvtT | scalars) ----
    int nb_dd = cdiv(E_DD, CHUNK), nb_dp = cdiv(E_DP, CHUNK), nb_cp = cdiv(E_CP, CHUNK);
    int ndb32 = ND / 32, npb32 = NPR / 32;
    int nT1 = (384 / 32) * (768 / 32);   // 288
    int nT2 = (768 / 32) * (256 / 32);   // 192
    int nsc = (ND + NPR + NCL) / 4;
    r16_mega<<<nb_dd + nb_dp + nb_cp + ndb32 + npb32 + nT1 + nT2 + nsc, 256, 0, stream>>>(
        ei_dd + E_DD, attr_dd, E_DD, nb_dd,
        dst_dp, E_DP, nb_dp,
        dst_cp, E_CP, nb_cp,
        ND, NCL,
        cnt_dd, attr_sum, cnt_dp, cnt_cp, rank_dd, rank_dp, rank_cp,
        drug_emb, x_drug, W_dd, H_dd, ndb32,
        protein_emb, x_protein, W_dp, W_cp, H_dp, H_cp, npb32,
        W1, Wt1, nT1, W2, Wt2, nT2,
        cell_emb, x_cell, wa,
        ssrc_dd, sdst_dd, sdst_dp, ssrc_dp, ssrc_cp, sdst_cp, NPR);

    // ---- scan -> scatter ----
    r16_exscan3<<<3, 1024, 0, stream>>>(cnt_dd, rs_dd, ND, cnt_dp, rs_dp, ND, cnt_cp, rs_cp, NCL);
    r16_scatter<<<cdiv(E_DD + ND + E_DP + E_CP, 256), 256, 0, stream>>>(
        ei_dd, attr_dd, E_DD, ND, src_dp, dst_dp, E_DP, src_cp, dst_cp, E_CP,
        rank_dd, rank_dp, rank_cp, cnt_dd, attr_sum, c_edge,
        ssrc_dd, sdst_dd, ssrc_dp, sdst_dp, ssrc_cp, sdst_cp,
        rs_dd, rs_dp, rs_cp, csr_dd, csr_dp, csr_cp);

    // ---- softmax + aggregate ----
    {
        int R = 2 * ND + NCL;
        int G = cdiv(R, 4) * 8;
        r16_agg3<<<G, 256, 0, stream>>>(
            rs_dd, csr_dd, (const uint*)H_dd, agg_dd, ND,
            rs_dp, csr_dp, (const uint*)H_dp, agg_dp,
            rs_cp, csr_cp, (const uint*)H_cp, agg_cp, R);
    }

    // ---- combine + relu + L2 normalize (fused) ----
    r16_fuse<<<ND + NCL, 128, 0, stream>>>(agg_dd, bias_dd, agg_dp, bias_dp, drugN, ND,
                                           agg_cp, bias_cp, cellN);

    // ---- batch gather + MLP (bf16 MFMA) ----
    r16_gather_hid<<<B, 128, 0, stream>>>(drugN, cellN, drug1, drug2, cellb, hidb);
    {
        dim3 g1(B / 128, 768 / 128);
        r16_mgemm<8, 1><<<g1, 256, 0, stream>>>(hidb, Wt1, b1, (void*)h1b, B, 384, 768);
        dim3 g2(B / 128, 256 / 64);
        r16_mgemm<4, 0><<<g2, 256, 0, stream>>>(h1b, Wt2, b2, (void*)h2, B, 768, 256);
    }
    r16_final<<<B / 4, 256, 0, stream>>>(h2, W3, b3, (float*)d_out);
}